// Round 3
// baseline (853.288 us; speedup 1.0000x reference)
//
#include <hip/hip_runtime.h>

// ---------------------------------------------------------------------------
// CNN + FC + 2x GraphSAGE, collapsed to scalar fields (GNN part is linear):
//   a = Wl1^T wl2, r1 = Wl1^T wr2, c = Wr1^T wl2, r2 = Wr1^T wr2  (5-vectors)
//   sa=a.h5, sr1=r1.h5, sc=c.h5, sr2=r2.h5  per (b,n)
//   out = mean2(mean1(sa)+sc) + kb1*[deg>0] + mean1(sr1) + sr2 + kb2 + bl2
// Fields stored plane-major [b][N] for fully coalesced writes and
// L2-resident per-plane aggregation.
// ---------------------------------------------------------------------------

__global__ __launch_bounds__(256) void k_mlp(
    const float* __restrict__ x,
    const float* __restrict__ w_t, const float* __restrict__ b_t,
    const float* __restrict__ w_r, const float* __restrict__ b_r,
    const float* __restrict__ w_tp, const float* __restrict__ b_tp,
    const float* __restrict__ w_ssr, const float* __restrict__ b_ssr,
    const float* __restrict__ f1w, const float* __restrict__ f1b,
    const float* __restrict__ f2w, const float* __restrict__ f2b,
    const float* __restrict__ g1_wl, const float* __restrict__ g1_wr,
    const float* __restrict__ g2_wl, const float* __restrict__ g2_wr,
    float* __restrict__ Sa, float* __restrict__ Sr1,
    float* __restrict__ Sc, float* __restrict__ Sr2,
    float* __restrict__ A1a, float* __restrict__ A1b, float* __restrict__ A2,
    int* __restrict__ degi, int N, int rows) {
  int rr = blockIdx.x * 256 + threadIdx.x;
  if (rr >= rows) return;

  // Load the full 108-float row; sched_barrier(0) pins all 27 loads BEFORE
  // any compute so they stay in flight together (compiler would sink them).
  const float4* xv = reinterpret_cast<const float4*>(x + (size_t)rr * 108);
  float4 v[27];
#pragma unroll
  for (int i = 0; i < 27; ++i) v[i] = xv[i];
  __builtin_amdgcn_sched_barrier(0);

  float feat[32];
#pragma unroll
  for (int i = 0; i < 3; ++i) {
    feat[4 * i + 0] = v[i].x; feat[4 * i + 1] = v[i].y;
    feat[4 * i + 2] = v[i].z; feat[4 * i + 3] = v[i].w;
  }
  const float* cw[4] = {w_t, w_r, w_tp, w_ssr};
  const float* cb[4] = {b_t, b_r, b_tp, b_ssr};
#pragma unroll
  for (int br = 0; br < 4; ++br) {
    float acc[5];
#pragma unroll
    for (int o = 0; o < 5; ++o) acc[o] = cb[br][o];
#pragma unroll
    for (int q = 0; q < 6; ++q) {
      float4 w4 = v[3 + 6 * br + q];
#pragma unroll
      for (int o = 0; o < 5; ++o) {
        acc[o] = fmaf(w4.x, cw[br][o * 24 + 4 * q + 0], acc[o]);
        acc[o] = fmaf(w4.y, cw[br][o * 24 + 4 * q + 1], acc[o]);
        acc[o] = fmaf(w4.z, cw[br][o * 24 + 4 * q + 2], acc[o]);
        acc[o] = fmaf(w4.w, cw[br][o * 24 + 4 * q + 3], acc[o]);
      }
    }
#pragma unroll
    for (int o = 0; o < 5; ++o) feat[12 + br * 5 + o] = fmaxf(acc[o], 0.f);
  }

  float h20[20];
#pragma unroll
  for (int o = 0; o < 20; ++o) {
    float acc = f1b[o];
#pragma unroll
    for (int i = 0; i < 32; ++i) acc = fmaf(feat[i], f1w[o * 32 + i], acc);
    h20[o] = fmaxf(acc, 0.f);
  }
  float h5[5];
#pragma unroll
  for (int o = 0; o < 5; ++o) {
    float acc = f2b[o];
#pragma unroll
    for (int i = 0; i < 20; ++i) acc = fmaf(h20[i], f2w[o * 20 + i], acc);
    h5[o] = acc;
  }

  float sa = 0.f, sr1 = 0.f, sc = 0.f, sr2 = 0.f;
#pragma unroll
  for (int j = 0; j < 20; ++j) {
    float t1 = 0.f, t2 = 0.f;
#pragma unroll
    for (int k = 0; k < 5; ++k) {
      t1 = fmaf(g1_wl[j * 5 + k], h5[k], t1);
      t2 = fmaf(g1_wr[j * 5 + k], h5[k], t2);
    }
    float wl2 = g2_wl[j], wr2 = g2_wr[j];
    sa  = fmaf(wl2, t1, sa);
    sr1 = fmaf(wr2, t1, sr1);
    sc  = fmaf(wl2, t2, sc);
    sr2 = fmaf(wr2, t2, sr2);
  }

  // rr = b*N + n : all writes fully coalesced (plane-major layout)
  Sa[rr] = sa; Sr1[rr] = sr1; Sc[rr] = sc; Sr2[rr] = sr2;
  A1a[rr] = 0.f; A1b[rr] = 0.f; A2[rr] = 0.f;
  if (rr < N) degi[rr] = 0;
}

// grid (E/256, 16): one b-plane per blockIdx.y -> L2-local gathers/atomics
__global__ void k_agg1(const int* __restrict__ src, const int* __restrict__ dst, int E,
                       const float* __restrict__ Sa, const float* __restrict__ Sr1,
                       float* __restrict__ A1a, float* __restrict__ A1b,
                       int* __restrict__ degi, int N) {
  int e = blockIdx.x * blockDim.x + threadIdx.x;
  if (e >= E) return;
  int b = blockIdx.y;
  int s = src[e], d = dst[e];
  size_t pb = (size_t)b * N;
  atomicAdd(&A1a[pb + d], Sa[pb + s]);
  atomicAdd(&A1b[pb + d], Sr1[pb + s]);
  if (b == 0) atomicAdd(&degi[d], 1);
}

// W = mean1(sa) + sc
__global__ void k_fin1(const float* __restrict__ A1a, const float* __restrict__ Sc,
                       const int* __restrict__ degi, float* __restrict__ W, int N) {
  int n = blockIdx.x * blockDim.x + threadIdx.x;
  if (n >= N) return;
  size_t t = (size_t)blockIdx.y * N + n;
  float inv = 1.0f / fmaxf((float)degi[n], 1.0f);
  W[t] = A1a[t] * inv + Sc[t];
}

__global__ void k_agg2(const int* __restrict__ src, const int* __restrict__ dst, int E,
                       const float* __restrict__ W, float* __restrict__ A2, int N) {
  int e = blockIdx.x * blockDim.x + threadIdx.x;
  if (e >= E) return;
  size_t pb = (size_t)blockIdx.y * N;
  int s = src[e], d = dst[e];
  atomicAdd(&A2[pb + d], W[pb + s]);
}

__global__ void k_final(const float* __restrict__ A1b, const float* __restrict__ Sr2,
                        const float* __restrict__ A2, const int* __restrict__ degi,
                        const float* __restrict__ g1_bl, const float* __restrict__ g2_wl,
                        const float* __restrict__ g2_wr, const float* __restrict__ g2_bl,
                        float* __restrict__ out, int N) {
  int n = blockIdx.x * blockDim.x + threadIdx.x;
  if (n >= N) return;
  size_t t = (size_t)blockIdx.y * N + n;
  float kb1 = 0.f, kb2 = 0.f;
#pragma unroll
  for (int j = 0; j < 20; ++j) {
    kb1 = fmaf(g2_wl[j], g1_bl[j], kb1);
    kb2 = fmaf(g2_wr[j], g1_bl[j], kb2);
  }
  int dg = degi[n];
  float inv = 1.0f / fmaxf((float)dg, 1.0f);
  float chi = dg > 0 ? 1.f : 0.f;
  out[t] = (A2[t] + A1b[t]) * inv + Sr2[t] + kb1 * chi + kb2 + g2_bl[0];
}

extern "C" void kernel_launch(void* const* d_in, const int* in_sizes, int n_in,
                              void* d_out, int out_size, void* d_ws, size_t ws_size,
                              hipStream_t stream) {
  const float* x     = (const float*)d_in[0];
  const int*   ei    = (const int*)d_in[1];
  const float* w_t   = (const float*)d_in[2];
  const float* b_t   = (const float*)d_in[3];
  const float* w_r   = (const float*)d_in[4];
  const float* b_r   = (const float*)d_in[5];
  const float* w_tp  = (const float*)d_in[6];
  const float* b_tp  = (const float*)d_in[7];
  const float* w_ssr = (const float*)d_in[8];
  const float* b_ssr = (const float*)d_in[9];
  const float* f1w   = (const float*)d_in[10];
  const float* f1b   = (const float*)d_in[11];
  const float* f2w   = (const float*)d_in[12];
  const float* f2b   = (const float*)d_in[13];
  const float* g1_wl = (const float*)d_in[14];
  const float* g1_bl = (const float*)d_in[15];
  const float* g1_wr = (const float*)d_in[16];
  const float* g2_wl = (const float*)d_in[17];
  const float* g2_bl = (const float*)d_in[18];
  const float* g2_wr = (const float*)d_in[19];
  float* out = (float*)d_out;

  const int E = in_sizes[1] / 2;
  const int N = out_size / 16;   // B = 16
  const int rows = out_size;     // N * B
  const int* src = ei;
  const int* dst = ei + E;

  // workspace: 8 plane-major fields of 16N floats + degi
  float* ws  = (float*)d_ws;
  float* Sa  = ws;                       // 16N
  float* Sr1 = Sa  + (size_t)16 * N;     // 16N
  float* Sc  = Sr1 + (size_t)16 * N;     // 16N
  float* Sr2 = Sc  + (size_t)16 * N;     // 16N
  float* A1a = Sr2 + (size_t)16 * N;     // 16N
  float* A1b = A1a + (size_t)16 * N;     // 16N
  float* A2  = A1b + (size_t)16 * N;     // 16N
  float* W   = A2  + (size_t)16 * N;     // 16N
  int* degi  = (int*)(W + (size_t)16 * N);

  k_mlp<<<(rows + 255) / 256, 256, 0, stream>>>(
      x, w_t, b_t, w_r, b_r, w_tp, b_tp, w_ssr, b_ssr,
      f1w, f1b, f2w, f2b, g1_wl, g1_wr, g2_wl, g2_wr,
      Sa, Sr1, Sc, Sr2, A1a, A1b, A2, degi, N, rows);

  dim3 gE((E + 255) / 256, 16);
  dim3 gN((N + 255) / 256, 16);
  k_agg1<<<gE, 256, 0, stream>>>(src, dst, E, Sa, Sr1, A1a, A1b, degi, N);
  k_fin1<<<gN, 256, 0, stream>>>(A1a, Sc, degi, W, N);
  k_agg2<<<gE, 256, 0, stream>>>(src, dst, E, W, A2, N);
  k_final<<<gN, 256, 0, stream>>>(A1b, Sr2, A2, degi, g1_bl, g2_wl, g2_wr, g2_bl, out, N);
}

// Round 4
// 140.004 us; speedup vs baseline: 6.0947x; 6.0947x over previous
//
#include <hip/hip_runtime.h>

// ---------------------------------------------------------------------------
// CNN + FC + 2x GraphSAGE, collapsed to scalar fields (GNN part is linear):
//   sa=a.h5, sr1=r1.h5, sc=c.h5, sr2=r2.h5 per (n,b)
//   W = mean1(sa)+sc ; out = mean2(W) + kb1*[deg>0] + mean1(sr1) + sr2 + kb2 + bl2
// Aggregation via per-call CSR + register-accumulating gather (NO f32 atomics).
// Fields interleaved [n][b] so gathers are 64-128B contiguous per 16-lane group.
// ---------------------------------------------------------------------------

__global__ void k_zero(int* __restrict__ cnt, int N) {
  int n = blockIdx.x * blockDim.x + threadIdx.x;
  if (n < N) cnt[n] = 0;
}

__global__ void k_count(const int* __restrict__ dst, int E, int* __restrict__ cnt) {
  int e = blockIdx.x * blockDim.x + threadIdx.x;
  if (e < E) atomicAdd(&cnt[dst[e]], 1);
}

// single block: exclusive scan cnt[N] -> row_ptr[N+1], plus cursor copy
__global__ __launch_bounds__(1024) void k_scan(const int* __restrict__ cnt, int N,
                                               int* __restrict__ row_ptr,
                                               int* __restrict__ cursor) {
  __shared__ int part[1024];
  int t = threadIdx.x;
  int chunk = (N + 1023) / 1024;
  int s0 = t * chunk, s1 = min(N, s0 + chunk);
  int sum = 0;
  for (int i = s0; i < s1; ++i) sum += cnt[i];
  part[t] = sum;
  __syncthreads();
  for (int off = 1; off < 1024; off <<= 1) {
    int v = (t >= off) ? part[t - off] : 0;
    __syncthreads();
    part[t] += v;
    __syncthreads();
  }
  int run = (t == 0) ? 0 : part[t - 1];
  for (int i = s0; i < s1; ++i) {
    row_ptr[i] = run; cursor[i] = run;
    run += cnt[i];
  }
  if (s1 == N) row_ptr[N] = run;  // all threads whose range ends at N agree
}

__global__ void k_scatter(const int* __restrict__ src, const int* __restrict__ dst, int E,
                          int* __restrict__ cursor, int* __restrict__ adj) {
  int e = blockIdx.x * blockDim.x + threadIdx.x;
  if (e < E) {
    int pos = atomicAdd(&cursor[dst[e]], 1);
    adj[pos] = src[e];
  }
}

// thread t: n = blk*16 + t/16, b = t%16 ; row rr = b*N+n of x.
// Field writes [n][b] are fully coalesced (512B per wave).
__global__ __launch_bounds__(256) void k_mlp(
    const float* __restrict__ x,
    const float* __restrict__ w_t, const float* __restrict__ b_t,
    const float* __restrict__ w_r, const float* __restrict__ b_r,
    const float* __restrict__ w_tp, const float* __restrict__ b_tp,
    const float* __restrict__ w_ssr, const float* __restrict__ b_ssr,
    const float* __restrict__ f1w, const float* __restrict__ f1b,
    const float* __restrict__ f2w, const float* __restrict__ f2b,
    const float* __restrict__ g1_wl, const float* __restrict__ g1_wr,
    const float* __restrict__ g2_wl, const float* __restrict__ g2_wr,
    float2* __restrict__ F1v, float2* __restrict__ F2v, int N) {
  int t = blockIdx.x * 256 + threadIdx.x;
  int n = t >> 4, b = t & 15;
  if (n >= N) return;
  size_t rr = (size_t)b * N + n;

  // hoist the full 432B row: 27 float4 loads pinned before compute
  const float4* xv = reinterpret_cast<const float4*>(x + rr * 108);
  float4 v[27];
#pragma unroll
  for (int i = 0; i < 27; ++i) v[i] = xv[i];
  __builtin_amdgcn_sched_barrier(0);

  float feat[32];
#pragma unroll
  for (int i = 0; i < 3; ++i) {
    feat[4 * i + 0] = v[i].x; feat[4 * i + 1] = v[i].y;
    feat[4 * i + 2] = v[i].z; feat[4 * i + 3] = v[i].w;
  }
  const float* cw[4] = {w_t, w_r, w_tp, w_ssr};
  const float* cb[4] = {b_t, b_r, b_tp, b_ssr};
#pragma unroll
  for (int br = 0; br < 4; ++br) {
    float acc[5];
#pragma unroll
    for (int o = 0; o < 5; ++o) acc[o] = cb[br][o];
#pragma unroll
    for (int q = 0; q < 6; ++q) {
      float4 w4 = v[3 + 6 * br + q];
#pragma unroll
      for (int o = 0; o < 5; ++o) {
        acc[o] = fmaf(w4.x, cw[br][o * 24 + 4 * q + 0], acc[o]);
        acc[o] = fmaf(w4.y, cw[br][o * 24 + 4 * q + 1], acc[o]);
        acc[o] = fmaf(w4.z, cw[br][o * 24 + 4 * q + 2], acc[o]);
        acc[o] = fmaf(w4.w, cw[br][o * 24 + 4 * q + 3], acc[o]);
      }
    }
#pragma unroll
    for (int o = 0; o < 5; ++o) feat[12 + br * 5 + o] = fmaxf(acc[o], 0.f);
  }

  float h20[20];
#pragma unroll
  for (int o = 0; o < 20; ++o) {
    float acc = f1b[o];
#pragma unroll
    for (int i = 0; i < 32; ++i) acc = fmaf(feat[i], f1w[o * 32 + i], acc);
    h20[o] = fmaxf(acc, 0.f);
  }
  float h5[5];
#pragma unroll
  for (int o = 0; o < 5; ++o) {
    float acc = f2b[o];
#pragma unroll
    for (int i = 0; i < 20; ++i) acc = fmaf(h20[i], f2w[o * 20 + i], acc);
    h5[o] = acc;
  }

  float sa = 0.f, sr1 = 0.f, sc = 0.f, sr2 = 0.f;
#pragma unroll
  for (int j = 0; j < 20; ++j) {
    float t1 = 0.f, t2 = 0.f;
#pragma unroll
    for (int k = 0; k < 5; ++k) {
      t1 = fmaf(g1_wl[j * 5 + k], h5[k], t1);
      t2 = fmaf(g1_wr[j * 5 + k], h5[k], t2);
    }
    float wl2 = g2_wl[j], wr2 = g2_wr[j];
    sa  = fmaf(wl2, t1, sa);
    sr1 = fmaf(wr2, t1, sr1);
    sc  = fmaf(wl2, t2, sc);
    sr2 = fmaf(wr2, t2, sr2);
  }

  F1v[n * 16 + b] = make_float2(sa, sr1);
  F2v[n * 16 + b] = make_float2(sc, sr2);
}

// 16 lanes per node (one per batch). Adjacency: coalesced 16-chunk load +
// __shfl broadcast. Gather F1v[s*16+b] = 128B contiguous per group.
__global__ void k_agg1(const int* __restrict__ row_ptr, const int* __restrict__ adj,
                       const float2* __restrict__ F1v, const float2* __restrict__ F2v,
                       float* __restrict__ W, float* __restrict__ V, int N) {
  int t = blockIdx.x * blockDim.x + threadIdx.x;
  int g = t >> 4, b = t & 15;
  if (g >= N) return;
  int beg = row_ptr[g], end = row_ptr[g + 1];
  float sa = 0.f, sb = 0.f;
  for (int c = beg; c < end; c += 16) {
    int idx = c + b;
    int a = adj[idx < end ? idx : end - 1];
    int m = min(16, end - c);
#pragma unroll 4
    for (int k = 0; k < m; ++k) {
      int s = __shfl(a, k, 16);
      float2 f = F1v[s * 16 + b];
      sa += f.x; sb += f.y;
    }
  }
  float inv = 1.0f / fmaxf((float)(end - beg), 1.0f);
  float2 f2 = F2v[t];  // t == g*16+b
  W[t] = sa * inv + f2.x;
  V[t] = sb * inv;
}

// second gather over W, fused with the final epilogue; LDS transpose so the
// out[b*N+n] write is coalesced per plane.
__global__ __launch_bounds__(256) void k_agg2(
    const int* __restrict__ row_ptr, const int* __restrict__ adj,
    const float* __restrict__ W, const float* __restrict__ V,
    const float2* __restrict__ F2v,
    const float* __restrict__ g1_bl, const float* __restrict__ g2_wl,
    const float* __restrict__ g2_wr, const float* __restrict__ g2_bl,
    float* __restrict__ out, int N) {
  __shared__ float tile[16][17];
  int t = blockIdx.x * 256 + threadIdx.x;
  int g = t >> 4, b = t & 15;
  float r = 0.f;
  if (g < N) {
    int beg = row_ptr[g], end = row_ptr[g + 1];
    float sw = 0.f;
    for (int c = beg; c < end; c += 16) {
      int idx = c + b;
      int a = adj[idx < end ? idx : end - 1];
      int m = min(16, end - c);
#pragma unroll 4
      for (int k = 0; k < m; ++k) {
        int s = __shfl(a, k, 16);
        sw += W[s * 16 + b];
      }
    }
    float kb1 = 0.f, kb2 = 0.f;
#pragma unroll
    for (int j = 0; j < 20; ++j) {
      kb1 = fmaf(g2_wl[j], g1_bl[j], kb1);
      kb2 = fmaf(g2_wr[j], g1_bl[j], kb2);
    }
    int deg = end - beg;
    float inv = 1.0f / fmaxf((float)deg, 1.0f);
    float chi = deg > 0 ? 1.f : 0.f;
    r = sw * inv + V[t] + F2v[t].y + kb1 * chi + kb2 + g2_bl[0];
  }
  // transpose in LDS: tile[b][node_local] then write coalesced per plane
  int gl = (threadIdx.x >> 4);          // local node 0..15
  tile[b][gl] = r;
  __syncthreads();
  int b2 = threadIdx.x >> 4;            // plane
  int gl2 = threadIdx.x & 15;           // local node
  int n2 = blockIdx.x * 16 + gl2;
  if (n2 < N) out[(size_t)b2 * N + n2] = tile[b2][gl2];
}

extern "C" void kernel_launch(void* const* d_in, const int* in_sizes, int n_in,
                              void* d_out, int out_size, void* d_ws, size_t ws_size,
                              hipStream_t stream) {
  const float* x     = (const float*)d_in[0];
  const int*   ei    = (const int*)d_in[1];
  const float* w_t   = (const float*)d_in[2];
  const float* b_t   = (const float*)d_in[3];
  const float* w_r   = (const float*)d_in[4];
  const float* b_r   = (const float*)d_in[5];
  const float* w_tp  = (const float*)d_in[6];
  const float* b_tp  = (const float*)d_in[7];
  const float* w_ssr = (const float*)d_in[8];
  const float* b_ssr = (const float*)d_in[9];
  const float* f1w   = (const float*)d_in[10];
  const float* f1b   = (const float*)d_in[11];
  const float* f2w   = (const float*)d_in[12];
  const float* f2b   = (const float*)d_in[13];
  const float* g1_wl = (const float*)d_in[14];
  const float* g1_bl = (const float*)d_in[15];
  const float* g1_wr = (const float*)d_in[16];
  const float* g2_wl = (const float*)d_in[17];
  const float* g2_bl = (const float*)d_in[18];
  const float* g2_wr = (const float*)d_in[19];
  float* out = (float*)d_out;

  const int E = in_sizes[1] / 2;
  const int N = out_size / 16;   // B = 16
  const int* src = ei;
  const int* dst = ei + E;

  // workspace
  float* ws  = (float*)d_ws;
  float2* F1v = (float2*)ws;                    // 16N float2
  float2* F2v = F1v + (size_t)16 * N;           // 16N float2
  float*  W   = (float*)(F2v + (size_t)16 * N); // 16N f32
  float*  V   = W + (size_t)16 * N;             // 16N f32
  int* cnt     = (int*)(V + (size_t)16 * N);    // N
  int* row_ptr = cnt + N;                       // N+1
  int* cursor  = row_ptr + N + 1;               // N
  int* adj     = cursor + N;                    // E

  int nb16 = (N * 16 + 255) / 256;

  k_zero<<<(N + 255) / 256, 256, 0, stream>>>(cnt, N);
  k_count<<<(E + 255) / 256, 256, 0, stream>>>(dst, E, cnt);
  k_scan<<<1, 1024, 0, stream>>>(cnt, N, row_ptr, cursor);
  k_scatter<<<(E + 255) / 256, 256, 0, stream>>>(src, dst, E, cursor, adj);
  k_mlp<<<nb16, 256, 0, stream>>>(
      x, w_t, b_t, w_r, b_r, w_tp, b_tp, w_ssr, b_ssr,
      f1w, f1b, f2w, f2b, g1_wl, g1_wr, g2_wl, g2_wr, F1v, F2v, N);
  k_agg1<<<nb16, 256, 0, stream>>>(row_ptr, adj, F1v, F2v, W, V, N);
  k_agg2<<<nb16, 256, 0, stream>>>(row_ptr, adj, W, V, F2v,
                                   g1_bl, g2_wl, g2_wr, g2_bl, out, N);
}